// Round 7
// baseline (186.551 us; speedup 1.0000x reference)
//
#include <hip/hip_runtime.h>
#include <math.h>

// Problem constants
#define BQ 2
#define LQ 2048
#define DQ 1024
#define HQ 16
#define HDQ 64

typedef __bf16 bf16_t;
typedef bf16_t bf16x4 __attribute__((ext_vector_type(4)));
typedef bf16_t bf16x8 __attribute__((ext_vector_type(8)));
typedef _Float16 f16_t;
typedef f16_t f16x4 __attribute__((ext_vector_type(4)));
typedef f16_t f16x8 __attribute__((ext_vector_type(8)));
typedef float f32x4 __attribute__((ext_vector_type(4)));

__device__ __forceinline__ bf16x8 cvt8(const float4 a, const float4 b) {
    bf16x8 o;
    o[0] = (bf16_t)a.x; o[1] = (bf16_t)a.y; o[2] = (bf16_t)a.z; o[3] = (bf16_t)a.w;
    o[4] = (bf16_t)b.x; o[5] = (bf16_t)b.y; o[6] = (bf16_t)b.z; o[7] = (bf16_t)b.w;
    return o;
}

// ---------------- prep: W transposes + packed rope table --------------------
// v2: x->bf16 conversion FUSED into qkv staging (removes 48 MB of HBM
// round-trip + 4096 blocks). grid 4224: [0,3072) Wqkv^T | [3072,4096)
// Wout^T | [4096,4224) rope pack rpk[l*16+i].
__global__ __launch_bounds__(256) void prep_kernel(
    const float* __restrict__ Wqkv, const float* __restrict__ Wout,
    const float* __restrict__ cosT, const float* __restrict__ sinT,
    bf16_t* __restrict__ Wqkvt, bf16_t* __restrict__ Wot,
    float4* __restrict__ rpk)
{
    __shared__ float t[32][33];
    const int bid = blockIdx.x, tid = threadIdx.x;
    if (bid < 4096) {
        const bool isq = bid < 3072;
        const int b = isq ? bid : bid - 3072;
        const int N = isq ? 3072 : 1024;
        const int gx = isq ? 96 : 32;
        const float* in = isq ? Wqkv : Wout;
        bf16_t* out = isq ? Wqkvt : Wot;
        const int k0 = (b / gx) * 32, n0 = (b % gx) * 32;
        const int r = tid >> 3, c4 = (tid & 7) * 4;
        float4 v = *(const float4*)(in + (size_t)(k0 + r) * N + n0 + c4);
        t[r][c4 + 0] = v.x; t[r][c4 + 1] = v.y;
        t[r][c4 + 2] = v.z; t[r][c4 + 3] = v.w;
        __syncthreads();
        bf16x4 o;
        o[0] = (bf16_t)t[c4 + 0][r]; o[1] = (bf16_t)t[c4 + 1][r];
        o[2] = (bf16_t)t[c4 + 2][r]; o[3] = (bf16_t)t[c4 + 3][r];
        *(bf16x4*)(out + (size_t)(n0 + r) * 1024 + k0 + c4) = o;
    } else {
        const int idx = (bid - 4096) * 256 + tid;   // 0..32767
        const int i = idx & 15, l = idx >> 4;
        rpk[idx] = make_float4(cosT[l * 64 + i], cosT[l * 64 + 16 + i],
                               sinT[l * 64 + i], sinT[l * 64 + 16 + i]);
    }
}

// ---------------- QKV GEMM: 128x128, BK=32 dbuf, 1 barrier/iter -------------
// A is read DIRECTLY from x (fp32) and converted to bf16 in the LDS-write
// phase (QWRITE runs after QCOMP -> loads get a full compute phase of
// latency cover; cvt VALU hides under MFMA, VALUBusy was only 13%).
// Per iter: {issue loads t+2 -> regs | ds_read frags buf[cur] | 16 MFMA |
// cvt+ds_write tile t+1 -> buf[cur^1] | ONE barrier}. Swizzle (4-chunk
// rows): store chunk c^((row>>1)&3), read chunk quad^((lr>>1)&3).
__global__ __launch_bounds__(256) void qkv_gemm_kernel(
    const float* __restrict__ X, const bf16_t* __restrict__ Bt,
    bf16_t* __restrict__ qo, bf16_t* __restrict__ ko, f16_t* __restrict__ vo,
    const float4* __restrict__ rpk)
{
    __shared__ __align__(16) bf16_t As[2][128][32];
    __shared__ __align__(16) bf16_t Bs[2][128][32];
    const int K = 1024;
    const int tid  = threadIdx.x;
    const int lane = tid & 63;
    const int w    = tid >> 6;
    const int lr   = lane & 15, quad = lane >> 4;
    const int wm   = w & 1, wn = w >> 1;
    const int m0   = blockIdx.y * 128, n0 = blockIdx.x * 128;

    // staging (BK=32): thread covers rows sr, sr+64 at 8-elem chunk sc
    const int sr  = tid >> 2;                      // 0..63
    const int sc  = tid & 3;                       // chunk 0..3
    const int sw  = (sc ^ ((sr >> 1) & 3)) * 8;    // swizzled LDS col (both halves)
    const int rdc = (quad ^ ((lr >> 1) & 3)) * 8;  // frag-read col

    const float*  Ar0 = X  + (size_t)(m0 + sr) * K + sc * 8;
    const float*  Ar1 = X  + (size_t)(m0 + sr + 64) * K + sc * 8;
    const bf16_t* Br0 = Bt + (size_t)(n0 + sr) * K + sc * 8;
    const bf16_t* Br1 = Bt + (size_t)(n0 + sr + 64) * K + sc * 8;

    f32x4 acc[4][4];
#pragma unroll
    for (int i = 0; i < 4; i++)
#pragma unroll
        for (int j = 0; j < 4; j++)
#pragma unroll
            for (int r = 0; r < 4; r++) acc[i][j][r] = 0.f;

#define QLOAD(FA, B0, B1, t) do {                          \
        FA[0] = *(const float4*)(Ar0 + (t) * 32);          \
        FA[1] = *(const float4*)(Ar0 + (t) * 32 + 4);      \
        FA[2] = *(const float4*)(Ar1 + (t) * 32);          \
        FA[3] = *(const float4*)(Ar1 + (t) * 32 + 4);      \
        B0 = *(const bf16x8*)(Br0 + (t) * 32);             \
        B1 = *(const bf16x8*)(Br1 + (t) * 32);             \
    } while (0)
#define QWRITE(FA, B0, B1, bf) do {                        \
        *(bf16x8*)(&As[bf][sr][sw])      = cvt8(FA[0], FA[1]); \
        *(bf16x8*)(&As[bf][sr + 64][sw]) = cvt8(FA[2], FA[3]); \
        *(bf16x8*)(&Bs[bf][sr][sw])      = B0;             \
        *(bf16x8*)(&Bs[bf][sr + 64][sw]) = B1;             \
    } while (0)
#define QCOMP(bf) do {                                                        \
        bf16x8 af[4], bfr[4];                                                 \
        _Pragma("unroll")                                                     \
        for (int tt = 0; tt < 4; tt++) {                                      \
            af[tt]  = *(const bf16x8*)(&As[bf][wm * 64 + tt * 16 + lr][rdc]); \
            bfr[tt] = *(const bf16x8*)(&Bs[bf][wn * 64 + tt * 16 + lr][rdc]); \
        }                                                                     \
        _Pragma("unroll")                                                     \
        for (int mt = 0; mt < 4; mt++)                                        \
            _Pragma("unroll")                                                 \
            for (int nt = 0; nt < 4; nt++)                                    \
                acc[mt][nt] = __builtin_amdgcn_mfma_f32_16x16x32_bf16(        \
                    af[mt], bfr[nt], acc[mt][nt], 0, 0, 0);                   \
    } while (0)

    float4 fa0[4], fa1[4];       // A staging (fp32), sets 0/1
    bf16x8 b00, b10, b01, b11;   // B staging, sets 0/1
    QLOAD(fa0, b00, b10, 0);
    QLOAD(fa1, b01, b11, 1);
    QWRITE(fa0, b00, b10, 0);
    __syncthreads();

    for (int t = 0; t < 32; t += 2) {
        if (t + 2 < 32) QLOAD(fa0, b00, b10, t + 2);
        QCOMP(0);
        QWRITE(fa1, b01, b11, 1);      // tile t+1 (2 iters in flight)
        __syncthreads();
        if (t + 3 < 32) QLOAD(fa1, b01, b11, t + 3);
        QCOMP(1);
        if (t + 2 < 32) QWRITE(fa0, b00, b10, 0);
        __syncthreads();
    }
#undef QLOAD
#undef QWRITE
#undef QCOMP

    const int which = n0 >> 10;                          // 0=q 1=k 2=v
    const int h = ((n0 & 1023) + wn * 64) >> 6;          // wave-uniform head
    if (which == 2) {
        // V: store transposed fp16 [B,H,HD,L]; r=0..3 consecutive l -> f16x4
#pragma unroll
        for (int mt = 0; mt < 4; mt++) {
            const int m = m0 + wm * 64 + mt * 16 + quad * 4;
            const int b = m >> 11, l = m & 2047;
            f16_t* p = vo + ((size_t)(b * HQ + h) * HDQ) * LQ + l;
#pragma unroll
            for (int nt = 0; nt < 4; nt++) {
                f16x4 pv;
#pragma unroll
                for (int r = 0; r < 4; r++) pv[r] = (f16_t)acc[mt][nt][r];
                *(f16x4*)(p + (size_t)(nt * 16 + lr) * LQ) = pv;
            }
        }
    } else {
        // Q/K: fused RoPE via packed table; Q gets softmax prescale
        bf16_t* dst = which ? ko : qo;
        const float qs = which ? 1.0f : 0.18033688011f;  // 0.125*log2(e)
#pragma unroll
        for (int mt = 0; mt < 4; mt++)
#pragma unroll
            for (int r = 0; r < 4; r++) {
                const int m = m0 + wm * 64 + mt * 16 + quad * 4 + r;
                const int b = m >> 11, l = m & 2047;
                const float4 rp = rpk[l * 16 + lr];
                const float a0 = acc[mt][0][r], a1 = acc[mt][1][r];
                const float a2 = acc[mt][2][r], a3 = acc[mt][3][r];
                bf16_t* p = dst + ((size_t)(b * HQ + h) * LQ + l) * HDQ;
                p[lr]      = (bf16_t)((a0 * rp.x - a2 * rp.z) * qs);
                p[16 + lr] = (bf16_t)((a1 * rp.y - a3 * rp.w) * qs);
                p[32 + lr] = (bf16_t)((a2 * rp.x + a0 * rp.z) * qs);
                p[48 + lr] = (bf16_t)((a3 * rp.y + a1 * rp.w) * qs);
            }
    }
}

// ---------------- Out GEMM: 64x128, BK=64, reg-prefetch pipeline ------------
__global__ __launch_bounds__(256) void out_gemm_kernel(
    const bf16_t* __restrict__ A, const bf16_t* __restrict__ Bt,
    float* __restrict__ fo, const float* __restrict__ bias)
{
    __shared__ __align__(16) bf16_t As[64][64];
    __shared__ __align__(16) bf16_t Bs[128][64];
    const int K = 1024, N = 1024;
    const int tid  = threadIdx.x;
    const int lane = tid & 63;
    const int w    = tid >> 6;
    const int lr   = lane & 15, quad = lane >> 4;
    const int m0   = blockIdx.y * 64, n0 = blockIdx.x * 128;
    const int srow8 = lane >> 3;
    const int swz   = ((lane & 7) ^ srow8) * 8;
    const int wc    = (lane & 7) * 8;

    f32x4 acc[4][2];
#pragma unroll
    for (int i = 0; i < 4; i++)
#pragma unroll
        for (int j = 0; j < 2; j++)
#pragma unroll
            for (int r = 0; r < 4; r++) acc[i][j][r] = 0.f;

    bf16x8 ar[2], br[4];
#pragma unroll
    for (int j = 0; j < 2; j++)
        ar[j] = *(const bf16x8*)(A + (size_t)(m0 + (w * 2 + j) * 8 + srow8) * K + swz);
#pragma unroll
    for (int j = 0; j < 4; j++)
        br[j] = *(const bf16x8*)(Bt + (size_t)(n0 + (w * 4 + j) * 8 + srow8) * K + swz);

    for (int k0 = 0; k0 < K; k0 += 64) {
        __syncthreads();
#pragma unroll
        for (int j = 0; j < 2; j++)
            *(bf16x8*)(&As[(w * 2 + j) * 8 + srow8][wc]) = ar[j];
#pragma unroll
        for (int j = 0; j < 4; j++)
            *(bf16x8*)(&Bs[(w * 4 + j) * 8 + srow8][wc]) = br[j];
        __syncthreads();
        if (k0 + 64 < K) {
#pragma unroll
            for (int j = 0; j < 2; j++)
                ar[j] = *(const bf16x8*)(A + (size_t)(m0 + (w * 2 + j) * 8 + srow8) * K
                                          + k0 + 64 + swz);
#pragma unroll
            for (int j = 0; j < 4; j++)
                br[j] = *(const bf16x8*)(Bt + (size_t)(n0 + (w * 4 + j) * 8 + srow8) * K
                                          + k0 + 64 + swz);
        }

        bf16x8 af[4][2], bfr[2][2];
#pragma unroll
        for (int h = 0; h < 2; h++) {
            const int cA = ((quad + 4 * h) ^ (lr & 7)) * 8;
#pragma unroll
            for (int t = 0; t < 4; t++)
                af[t][h] = *(const bf16x8*)(&As[t * 16 + lr][cA]);
#pragma unroll
            for (int t = 0; t < 2; t++)
                bfr[t][h] = *(const bf16x8*)(&Bs[w * 32 + t * 16 + lr][cA]);
        }
#pragma unroll
        for (int h = 0; h < 2; h++)
#pragma unroll
            for (int mt = 0; mt < 4; mt++)
#pragma unroll
                for (int nt = 0; nt < 2; nt++)
                    acc[mt][nt] = __builtin_amdgcn_mfma_f32_16x16x32_bf16(
                        af[mt][h], bfr[nt][h], acc[mt][nt], 0, 0, 0);
    }

#pragma unroll
    for (int nt = 0; nt < 2; nt++) {
        const int n = n0 + w * 32 + nt * 16 + lr;
        const float bj = bias[n];
#pragma unroll
        for (int mt = 0; mt < 4; mt++)
#pragma unroll
            for (int r = 0; r < 4; r++) {
                const int m = m0 + mt * 16 + quad * 4 + r;
                fo[(size_t)m * N + n] = acc[mt][nt][r] + bj;
            }
    }
}

// ---------------- bf16/fp16 MFMA flash attention v10 ------------------------
// v10: V tile pad 64 -> 68 f16 (136 B row = 34 banks) — fixed the 4.33M
// conflict cycles (R4->R5: attn -7 us, conflict theory exact-match).
// K tile keeps the verified XOR-swizzle. setprio kept.
__global__ __launch_bounds__(512) void attn_kernel10(
    const bf16_t* __restrict__ qb, const bf16_t* __restrict__ kb,
    const f16_t* __restrict__ vtb, bf16_t* __restrict__ ob)
{
    __shared__ __align__(16) bf16_t Kb[2][64][64];
    __shared__ __align__(16) f16_t  Vs[2][64][68];

    const int tid  = threadIdx.x;
    const int lane = tid & 63;
    const int w    = tid >> 6;           // 0..7
    const int quad = lane >> 4;
    const int lr   = lane & 15;
    const int bh   = blockIdx.x;
    const int qt2  = 15 - blockIdx.y;    // heavy blocks first

    const bf16_t* Kh = kb  + (size_t)bh * LQ * HDQ;
    const f16_t*  Vh = vtb + (size_t)bh * HDQ * LQ;

    const int r0  = tid >> 3;                    // 0..63
    const int c0  = (tid & 7) * 8;
    const int ksw = ((tid & 7) ^ (r0 & 7)) * 8;  // swizzled chunk (K store)

    f16x4 ones;
#pragma unroll
    for (int j = 0; j < 4; j++) ones[j] = (f16_t)1.0f;

    const int qbase = qt2 * 128 + w * 16;        // wave's first q row
    const int qrow  = qbase + lr;
    const bf16_t* qp = qb + ((size_t)bh * LQ + qrow) * HDQ;
    const bf16x8 qa0 = *(const bf16x8*)(qp + quad * 8);
    const bf16x8 qa1 = *(const bf16x8*)(qp + 32 + quad * 8);

    const int nkt = 2 * qt2 + 2;                 // kv tiles for this block

    bf16x8 kp = *(const bf16x8*)(Kh + (size_t)r0 * HDQ + c0);
    f16x8  vp = *(const f16x8*)(Vh + (size_t)r0 * LQ + c0);

    f32x4 Oacc[4], lacc;
#pragma unroll
    for (int d = 0; d < 4; d++)
#pragma unroll
        for (int r = 0; r < 4; r++) Oacc[d][r] = 0.f;
#pragma unroll
    for (int r = 0; r < 4; r++) lacc[r] = 0.f;

    for (int kt = 0; kt < nkt; kt++) {
        const int buf = kt & 1;
        *(bf16x8*)(&Kb[buf][r0][ksw]) = kp;
        *(f16x8*)(&Vs[buf][r0][c0]) = vp;
        __syncthreads();
        if (kt + 1 < nkt) {
            kp = *(const bf16x8*)(Kh + (size_t)((kt + 1) * 64 + r0) * HDQ + c0);
            vp = *(const f16x8*)(Vh + (size_t)r0 * LQ + (kt + 1) * 64 + c0);
        }

        if (kt * 64 <= qbase + 15) {             // else fully masked: skip
            // S^T = K Q^T  (row=kv=quad*4+r, col=q=lr), exp2-domain
            f32x4 s[4];
            __builtin_amdgcn_s_setprio(1);
#pragma unroll
            for (int nt = 0; nt < 4; nt++) {
                const int rsw = lr & 7;          // row&7 of K frag row
                const bf16x8 kf0 = *(const bf16x8*)(&Kb[buf][nt * 16 + lr][(quad ^ rsw) * 8]);
                const bf16x8 kf1 = *(const bf16x8*)(&Kb[buf][nt * 16 + lr][((quad + 4) ^ rsw) * 8]);
                f32x4 z = {0.f, 0.f, 0.f, 0.f};
                z = __builtin_amdgcn_mfma_f32_16x16x32_bf16(kf0, qa0, z, 0, 0, 0);
                z = __builtin_amdgcn_mfma_f32_16x16x32_bf16(kf1, qa1, z, 0, 0, 0);
                s[nt] = z;
            }
            __builtin_amdgcn_s_setprio(0);
            if (kt * 64 + 63 > qbase) {          // partial diagonal tile
#pragma unroll
                for (int nt = 0; nt < 4; nt++)
#pragma unroll
                    for (int r = 0; r < 4; r++)
                        if (kt * 64 + nt * 16 + quad * 4 + r > qrow) s[nt][r] = -INFINITY;
            }
            f16x4 pa[4];
#pragma unroll
            for (int nt = 0; nt < 4; nt++)
#pragma unroll
                for (int r = 0; r < 4; r++)
                    pa[nt][r] = (f16_t)__builtin_amdgcn_exp2f(s[nt][r]);

            // O += P V (16x16x16 f16), l += row-sum(P)
            __builtin_amdgcn_s_setprio(1);
#pragma unroll
            for (int d = 0; d < 4; d++)
#pragma unroll
                for (int nt = 0; nt < 4; nt++) {
                    const f16x4 vf = *(const f16x4*)(&Vs[buf][d * 16 + lr][nt * 16 + quad * 4]);
                    Oacc[d] = __builtin_amdgcn_mfma_f32_16x16x16f16(pa[nt], vf, Oacc[d], 0, 0, 0);
                }
#pragma unroll
            for (int nt = 0; nt < 4; nt++)
                lacc = __builtin_amdgcn_mfma_f32_16x16x16f16(pa[nt], ones, lacc, 0, 0, 0);
            __builtin_amdgcn_s_setprio(0);
        }
    }

    // epilogue: O / l -> ob [B, L, H*HD] bf16  (row=q=quad*4+r, col=d=lr)
    const int b = bh >> 4, h = bh & 15;
#pragma unroll
    for (int r = 0; r < 4; r++) {
        const float inv = 1.0f / lacc[r];
        const int q = qbase + quad * 4 + r;
        bf16_t* op = ob + ((size_t)(b * LQ + q)) * 1024 + h * 64;
#pragma unroll
        for (int d = 0; d < 4; d++)
            op[d * 16 + lr] = (bf16_t)(Oacc[d][r] * inv);
    }
}

// ---------------- launch -----------------------------------------------------
extern "C" void kernel_launch(void* const* d_in, const int* in_sizes, int n_in,
                              void* d_out, int out_size, void* d_ws, size_t ws_size,
                              hipStream_t stream) {
    const float* x        = (const float*)d_in[0];
    const float* rope_cos = (const float*)d_in[1];
    const float* rope_sin = (const float*)d_in[2];
    const float* W_qkv    = (const float*)d_in[3];
    const float* W_out    = (const float*)d_in[4];
    const float* b_out    = (const float*)d_in[5];
    float* out = (float*)d_out;

    // ws (bytes): (xb slot unused) | qb 8M | kb 8M | vth 8M | ob 8M |
    // Wqkvt 6M | Wot 2M | rpk 0.5M
    char* wsb = (char*)d_ws;
    bf16_t* qbf   = (bf16_t*)(wsb + ((size_t)8  << 20));
    bf16_t* kbf   = (bf16_t*)(wsb + ((size_t)16 << 20));
    f16_t*  vth   = (f16_t*) (wsb + ((size_t)24 << 20));
    bf16_t* ob    = (bf16_t*)(wsb + ((size_t)32 << 20));
    bf16_t* Wqkvt = (bf16_t*)(wsb + ((size_t)40 << 20));
    bf16_t* Wot   = (bf16_t*)(wsb + ((size_t)46 << 20));
    float4* rpk   = (float4*)(wsb + ((size_t)48 << 20));

    prep_kernel<<<4224, 256, 0, stream>>>(W_qkv, W_out, rope_cos, rope_sin,
                                          Wqkvt, Wot, rpk);

    dim3 g1(3072 / 128, 4096 / 128);
    qkv_gemm_kernel<<<g1, 256, 0, stream>>>(x, Wqkvt, qbf, kbf, vth, rpk);

    dim3 g2(32, 16);   // x = bh (L2 locality), y -> qt2 = 15-y (heavy first)
    attn_kernel10<<<g2, 512, 0, stream>>>(qbf, kbf, vth, ob);

    dim3 g3(1024 / 128, 4096 / 64);
    out_gemm_kernel<<<g3, 256, 0, stream>>>(ob, Wot, out, b_out);
}

// Round 9
// 174.482 us; speedup vs baseline: 1.0692x; 1.0692x over previous
//
#include <hip/hip_runtime.h>
#include <math.h>

// Problem constants
#define BQ 2
#define LQ 2048
#define DQ 1024
#define HQ 16
#define HDQ 64

typedef __bf16 bf16_t;
typedef bf16_t bf16x4 __attribute__((ext_vector_type(4)));
typedef bf16_t bf16x8 __attribute__((ext_vector_type(8)));
typedef _Float16 f16_t;
typedef f16_t f16x4 __attribute__((ext_vector_type(4)));
typedef f16_t f16x8 __attribute__((ext_vector_type(8)));
typedef float f32x4 __attribute__((ext_vector_type(4)));

// ---------------- fused prep: x->bf16, W transposes, packed rope table ------
// grid 8320: [0,4096) convert x | [4096,7168) Wqkv^T | [7168,8192) Wout^T |
// [8192,8320) rope pack rpk[l*16+i] = (cos_i, cos_{16+i}, sin_i, sin_{16+i})
// (R7 tried fusing the x-conversion into qkv's A-fetch: qkv 42.7->62.8 us,
//  FETCH +35 MB — the fp32 A-path broke the prefetch cover. Reverted.)
__global__ __launch_bounds__(256) void prep_kernel(
    const float* __restrict__ x, const float* __restrict__ Wqkv,
    const float* __restrict__ Wout, const float* __restrict__ cosT,
    const float* __restrict__ sinT,
    bf16_t* __restrict__ xb, bf16_t* __restrict__ Wqkvt,
    bf16_t* __restrict__ Wot, float4* __restrict__ rpk)
{
    __shared__ float t[32][33];
    const int bid = blockIdx.x, tid = threadIdx.x;
    if (bid < 4096) {
        const int i = (bid * 256 + tid) * 4;
        float4 v = *(const float4*)(x + i);
        bf16x4 o;
        o[0] = (bf16_t)v.x; o[1] = (bf16_t)v.y; o[2] = (bf16_t)v.z; o[3] = (bf16_t)v.w;
        *(bf16x4*)(xb + i) = o;
    } else if (bid < 8192) {
        const bool isq = bid < 7168;
        const int b = isq ? bid - 4096 : bid - 7168;
        const int N = isq ? 3072 : 1024;
        const int gx = isq ? 96 : 32;
        const float* in = isq ? Wqkv : Wout;
        bf16_t* out = isq ? Wqkvt : Wot;
        const int k0 = (b / gx) * 32, n0 = (b % gx) * 32;
        const int r = tid >> 3, c4 = (tid & 7) * 4;
        float4 v = *(const float4*)(in + (size_t)(k0 + r) * N + n0 + c4);
        t[r][c4 + 0] = v.x; t[r][c4 + 1] = v.y;
        t[r][c4 + 2] = v.z; t[r][c4 + 3] = v.w;
        __syncthreads();
        bf16x4 o;
        o[0] = (bf16_t)t[c4 + 0][r]; o[1] = (bf16_t)t[c4 + 1][r];
        o[2] = (bf16_t)t[c4 + 2][r]; o[3] = (bf16_t)t[c4 + 3][r];
        *(bf16x4*)(out + (size_t)(n0 + r) * 1024 + k0 + c4) = o;
    } else {
        const int idx = (bid - 8192) * 256 + tid;   // 0..32767
        const int i = idx & 15, l = idx >> 4;
        rpk[idx] = make_float4(cosT[l * 64 + i], cosT[l * 64 + 16 + i],
                               sinT[l * 64 + i], sinT[l * 64 + 16 + i]);
    }
}

// ---------------- QKV GEMM: 128x128, BK=32 dbuf, 1 barrier/iter -------------
// Per iter: {issue loads t+2 -> regs | ds_read frags buf[cur] | 16 MFMA |
// ds_write tile t+1 -> buf[cur^1] | ONE barrier}. Loads ride 2 full
// iterations; ds_writes overlap the MFMA window. Swizzle (4-chunk rows):
// store chunk c^((row>>1)&3), read chunk quad^((lr>>1)&3) -> conflict-free.
__global__ __launch_bounds__(256) void qkv_gemm_kernel(
    const bf16_t* __restrict__ A, const bf16_t* __restrict__ Bt,
    bf16_t* __restrict__ qo, bf16_t* __restrict__ ko, f16_t* __restrict__ vo,
    const float4* __restrict__ rpk)
{
    __shared__ __align__(16) bf16_t As[2][128][32];
    __shared__ __align__(16) bf16_t Bs[2][128][32];
    const int K = 1024;
    const int tid  = threadIdx.x;
    const int lane = tid & 63;
    const int w    = tid >> 6;
    const int lr   = lane & 15, quad = lane >> 4;
    const int wm   = w & 1, wn = w >> 1;
    const int m0   = blockIdx.y * 128, n0 = blockIdx.x * 128;

    const int sr  = tid >> 2;                      // 0..63
    const int sc  = tid & 3;                       // chunk 0..3
    const int sw  = (sc ^ ((sr >> 1) & 3)) * 8;    // swizzled LDS col
    const int rdc = (quad ^ ((lr >> 1) & 3)) * 8;  // frag-read col

    const bf16_t* Ar0 = A  + (size_t)(m0 + sr) * K + sc * 8;
    const bf16_t* Ar1 = A  + (size_t)(m0 + sr + 64) * K + sc * 8;
    const bf16_t* Br0 = Bt + (size_t)(n0 + sr) * K + sc * 8;
    const bf16_t* Br1 = Bt + (size_t)(n0 + sr + 64) * K + sc * 8;

    f32x4 acc[4][4];
#pragma unroll
    for (int i = 0; i < 4; i++)
#pragma unroll
        for (int j = 0; j < 4; j++)
#pragma unroll
            for (int r = 0; r < 4; r++) acc[i][j][r] = 0.f;

#define QLOAD(A0, A1, B0, B1, t) do {                      \
        A0 = *(const bf16x8*)(Ar0 + (t) * 32);             \
        A1 = *(const bf16x8*)(Ar1 + (t) * 32);             \
        B0 = *(const bf16x8*)(Br0 + (t) * 32);             \
        B1 = *(const bf16x8*)(Br1 + (t) * 32);             \
    } while (0)
#define QWRITE(A0, A1, B0, B1, bf) do {                    \
        *(bf16x8*)(&As[bf][sr][sw])      = A0;             \
        *(bf16x8*)(&As[bf][sr + 64][sw]) = A1;             \
        *(bf16x8*)(&Bs[bf][sr][sw])      = B0;             \
        *(bf16x8*)(&Bs[bf][sr + 64][sw]) = B1;             \
    } while (0)
#define QCOMP(bf) do {                                                        \
        bf16x8 af[4], bfr[4];                                                 \
        _Pragma("unroll")                                                     \
        for (int tt = 0; tt < 4; tt++) {                                      \
            af[tt]  = *(const bf16x8*)(&As[bf][wm * 64 + tt * 16 + lr][rdc]); \
            bfr[tt] = *(const bf16x8*)(&Bs[bf][wn * 64 + tt * 16 + lr][rdc]); \
        }                                                                     \
        _Pragma("unroll")                                                     \
        for (int mt = 0; mt < 4; mt++)                                        \
            _Pragma("unroll")                                                 \
            for (int nt = 0; nt < 4; nt++)                                    \
                acc[mt][nt] = __builtin_amdgcn_mfma_f32_16x16x32_bf16(        \
                    af[mt], bfr[nt], acc[mt][nt], 0, 0, 0);                   \
    } while (0)

    bf16x8 a00, a10, b00, b10;   // staging set 0 (even tiles)
    bf16x8 a01, a11, b01, b11;   // staging set 1 (odd tiles)
    QLOAD(a00, a10, b00, b10, 0);
    QLOAD(a01, a11, b01, b11, 1);
    QWRITE(a00, a10, b00, b10, 0);
    __syncthreads();

    for (int t = 0; t < 32; t += 2) {
        if (t + 2 < 32) QLOAD(a00, a10, b00, b10, t + 2);
        QCOMP(0);
        QWRITE(a01, a11, b01, b11, 1);      // tile t+1 (2 iters in flight)
        __syncthreads();
        if (t + 3 < 32) QLOAD(a01, a11, b01, b11, t + 3);
        QCOMP(1);
        if (t + 2 < 32) QWRITE(a00, a10, b00, b10, 0);
        __syncthreads();
    }
#undef QLOAD
#undef QWRITE
#undef QCOMP

    const int which = n0 >> 10;                          // 0=q 1=k 2=v
    const int h = ((n0 & 1023) + wn * 64) >> 6;          // wave-uniform head
    if (which == 2) {
        // V: store transposed fp16 [B,H,HD,L]; r=0..3 consecutive l -> f16x4
#pragma unroll
        for (int mt = 0; mt < 4; mt++) {
            const int m = m0 + wm * 64 + mt * 16 + quad * 4;
            const int b = m >> 11, l = m & 2047;
            f16_t* p = vo + ((size_t)(b * HQ + h) * HDQ) * LQ + l;
#pragma unroll
            for (int nt = 0; nt < 4; nt++) {
                f16x4 pv;
#pragma unroll
                for (int r = 0; r < 4; r++) pv[r] = (f16_t)acc[mt][nt][r];
                *(f16x4*)(p + (size_t)(nt * 16 + lr) * LQ) = pv;
            }
        }
    } else {
        // Q/K: fused RoPE via packed table; Q gets softmax prescale
        bf16_t* dst = which ? ko : qo;
        const float qs = which ? 1.0f : 0.18033688011f;  // 0.125*log2(e)
#pragma unroll
        for (int mt = 0; mt < 4; mt++)
#pragma unroll
            for (int r = 0; r < 4; r++) {
                const int m = m0 + wm * 64 + mt * 16 + quad * 4 + r;
                const int b = m >> 11, l = m & 2047;
                const float4 rp = rpk[l * 16 + lr];
                const float a0 = acc[mt][0][r], a1 = acc[mt][1][r];
                const float a2 = acc[mt][2][r], a3 = acc[mt][3][r];
                bf16_t* p = dst + ((size_t)(b * HQ + h) * LQ + l) * HDQ;
                p[lr]      = (bf16_t)((a0 * rp.x - a2 * rp.z) * qs);
                p[16 + lr] = (bf16_t)((a1 * rp.y - a3 * rp.w) * qs);
                p[32 + lr] = (bf16_t)((a2 * rp.x + a0 * rp.z) * qs);
                p[48 + lr] = (bf16_t)((a3 * rp.y + a1 * rp.w) * qs);
            }
    }
}

// ---------------- Out GEMM: 64x128, BK=32 dbuf, 1 barrier/iter --------------
// Same verified pipeline/swizzle as qkv BK=32 (qkv: 44.3 -> <=42.7 us).
// A tile 64 rows: each thread stages 1 A-chunk + 2 B-chunks per K-tile.
__global__ __launch_bounds__(256) void out_gemm_kernel(
    const bf16_t* __restrict__ A, const bf16_t* __restrict__ Bt,
    float* __restrict__ fo, const float* __restrict__ bias)
{
    __shared__ __align__(16) bf16_t As[2][64][32];
    __shared__ __align__(16) bf16_t Bs[2][128][32];
    const int K = 1024, N = 1024;
    const int tid  = threadIdx.x;
    const int lane = tid & 63;
    const int w    = tid >> 6;
    const int lr   = lane & 15, quad = lane >> 4;
    const int m0   = blockIdx.y * 64, n0 = blockIdx.x * 128;

    const int sr  = tid >> 2;                      // 0..63
    const int sc  = tid & 3;                       // chunk 0..3
    const int sw  = (sc ^ ((sr >> 1) & 3)) * 8;    // swizzled LDS col
    const int rdc = (quad ^ ((lr >> 1) & 3)) * 8;  // frag-read col

    const bf16_t* Ar0 = A  + (size_t)(m0 + sr) * K + sc * 8;
    const bf16_t* Br0 = Bt + (size_t)(n0 + sr) * K + sc * 8;
    const bf16_t* Br1 = Bt + (size_t)(n0 + sr + 64) * K + sc * 8;

    f32x4 acc[4][2];
#pragma unroll
    for (int i = 0; i < 4; i++)
#pragma unroll
        for (int j = 0; j < 2; j++)
#pragma unroll
            for (int r = 0; r < 4; r++) acc[i][j][r] = 0.f;

#define OLOAD(A0, B0, B1, t) do {                          \
        A0 = *(const bf16x8*)(Ar0 + (t) * 32);             \
        B0 = *(const bf16x8*)(Br0 + (t) * 32);             \
        B1 = *(const bf16x8*)(Br1 + (t) * 32);             \
    } while (0)
#define OWRITE(A0, B0, B1, bf) do {                        \
        *(bf16x8*)(&As[bf][sr][sw])      = A0;             \
        *(bf16x8*)(&Bs[bf][sr][sw])      = B0;             \
        *(bf16x8*)(&Bs[bf][sr + 64][sw]) = B1;             \
    } while (0)
#define OCOMP(bf) do {                                                        \
        bf16x8 af[4], bfr[2];                                                 \
        _Pragma("unroll")                                                     \
        for (int tt = 0; tt < 4; tt++)                                        \
            af[tt]  = *(const bf16x8*)(&As[bf][tt * 16 + lr][rdc]);           \
        _Pragma("unroll")                                                     \
        for (int tt = 0; tt < 2; tt++)                                        \
            bfr[tt] = *(const bf16x8*)(&Bs[bf][w * 32 + tt * 16 + lr][rdc]);  \
        _Pragma("unroll")                                                     \
        for (int mt = 0; mt < 4; mt++)                                        \
            _Pragma("unroll")                                                 \
            for (int nt = 0; nt < 2; nt++)                                    \
                acc[mt][nt] = __builtin_amdgcn_mfma_f32_16x16x32_bf16(        \
                    af[mt], bfr[nt], acc[mt][nt], 0, 0, 0);                   \
    } while (0)

    bf16x8 a0s0, b0s0, b1s0;
    bf16x8 a0s1, b0s1, b1s1;
    OLOAD(a0s0, b0s0, b1s0, 0);
    OLOAD(a0s1, b0s1, b1s1, 1);
    OWRITE(a0s0, b0s0, b1s0, 0);
    __syncthreads();

    for (int t = 0; t < 32; t += 2) {
        if (t + 2 < 32) OLOAD(a0s0, b0s0, b1s0, t + 2);
        OCOMP(0);
        OWRITE(a0s1, b0s1, b1s1, 1);
        __syncthreads();
        if (t + 3 < 32) OLOAD(a0s1, b0s1, b1s1, t + 3);
        OCOMP(1);
        if (t + 2 < 32) OWRITE(a0s0, b0s0, b1s0, 0);
        __syncthreads();
    }
#undef OLOAD
#undef OWRITE
#undef OCOMP

#pragma unroll
    for (int nt = 0; nt < 2; nt++) {
        const int n = n0 + w * 32 + nt * 16 + lr;
        const float bj = bias[n];
#pragma unroll
        for (int mt = 0; mt < 4; mt++)
#pragma unroll
            for (int r = 0; r < 4; r++) {
                const int m = m0 + mt * 16 + quad * 4 + r;
                fo[(size_t)m * N + n] = acc[mt][nt][r] + bj;
            }
    }
}

// ---------------- bf16/fp16 MFMA flash attention v10 ------------------------
// v10: V tile pad 64 -> 68 f16 (136 B row = 34 banks) — fixed the 4.33M
// conflict cycles (R4->R5: attn -7 us, conflict theory exact-match).
// K tile keeps the verified XOR-swizzle. setprio kept.
__global__ __launch_bounds__(512) void attn_kernel10(
    const bf16_t* __restrict__ qb, const bf16_t* __restrict__ kb,
    const f16_t* __restrict__ vtb, bf16_t* __restrict__ ob)
{
    __shared__ __align__(16) bf16_t Kb[2][64][64];
    __shared__ __align__(16) f16_t  Vs[2][64][68];

    const int tid  = threadIdx.x;
    const int lane = tid & 63;
    const int w    = tid >> 6;           // 0..7
    const int quad = lane >> 4;
    const int lr   = lane & 15;
    const int bh   = blockIdx.x;
    const int qt2  = 15 - blockIdx.y;    // heavy blocks first

    const bf16_t* Kh = kb  + (size_t)bh * LQ * HDQ;
    const f16_t*  Vh = vtb + (size_t)bh * HDQ * LQ;

    const int r0  = tid >> 3;                    // 0..63
    const int c0  = (tid & 7) * 8;
    const int ksw = ((tid & 7) ^ (r0 & 7)) * 8;  // swizzled chunk (K store)

    f16x4 ones;
#pragma unroll
    for (int j = 0; j < 4; j++) ones[j] = (f16_t)1.0f;

    const int qbase = qt2 * 128 + w * 16;        // wave's first q row
    const int qrow  = qbase + lr;
    const bf16_t* qp = qb + ((size_t)bh * LQ + qrow) * HDQ;
    const bf16x8 qa0 = *(const bf16x8*)(qp + quad * 8);
    const bf16x8 qa1 = *(const bf16x8*)(qp + 32 + quad * 8);

    const int nkt = 2 * qt2 + 2;                 // kv tiles for this block

    bf16x8 kp = *(const bf16x8*)(Kh + (size_t)r0 * HDQ + c0);
    f16x8  vp = *(const f16x8*)(Vh + (size_t)r0 * LQ + c0);

    f32x4 Oacc[4], lacc;
#pragma unroll
    for (int d = 0; d < 4; d++)
#pragma unroll
        for (int r = 0; r < 4; r++) Oacc[d][r] = 0.f;
#pragma unroll
    for (int r = 0; r < 4; r++) lacc[r] = 0.f;

    for (int kt = 0; kt < nkt; kt++) {
        const int buf = kt & 1;
        *(bf16x8*)(&Kb[buf][r0][ksw]) = kp;
        *(f16x8*)(&Vs[buf][r0][c0]) = vp;
        __syncthreads();
        if (kt + 1 < nkt) {
            kp = *(const bf16x8*)(Kh + (size_t)((kt + 1) * 64 + r0) * HDQ + c0);
            vp = *(const f16x8*)(Vh + (size_t)r0 * LQ + (kt + 1) * 64 + c0);
        }

        if (kt * 64 <= qbase + 15) {             // else fully masked: skip
            // S^T = K Q^T  (row=kv=quad*4+r, col=q=lr), exp2-domain
            f32x4 s[4];
            __builtin_amdgcn_s_setprio(1);
#pragma unroll
            for (int nt = 0; nt < 4; nt++) {
                const int rsw = lr & 7;          // row&7 of K frag row
                const bf16x8 kf0 = *(const bf16x8*)(&Kb[buf][nt * 16 + lr][(quad ^ rsw) * 8]);
                const bf16x8 kf1 = *(const bf16x8*)(&Kb[buf][nt * 16 + lr][((quad + 4) ^ rsw) * 8]);
                f32x4 z = {0.f, 0.f, 0.f, 0.f};
                z = __builtin_amdgcn_mfma_f32_16x16x32_bf16(kf0, qa0, z, 0, 0, 0);
                z = __builtin_amdgcn_mfma_f32_16x16x32_bf16(kf1, qa1, z, 0, 0, 0);
                s[nt] = z;
            }
            __builtin_amdgcn_s_setprio(0);
            if (kt * 64 + 63 > qbase) {          // partial diagonal tile
#pragma unroll
                for (int nt = 0; nt < 4; nt++)
#pragma unroll
                    for (int r = 0; r < 4; r++)
                        if (kt * 64 + nt * 16 + quad * 4 + r > qrow) s[nt][r] = -INFINITY;
            }
            f16x4 pa[4];
#pragma unroll
            for (int nt = 0; nt < 4; nt++)
#pragma unroll
                for (int r = 0; r < 4; r++)
                    pa[nt][r] = (f16_t)__builtin_amdgcn_exp2f(s[nt][r]);

            // O += P V (16x16x16 f16), l += row-sum(P)
            __builtin_amdgcn_s_setprio(1);
#pragma unroll
            for (int d = 0; d < 4; d++)
#pragma unroll
                for (int nt = 0; nt < 4; nt++) {
                    const f16x4 vf = *(const f16x4*)(&Vs[buf][d * 16 + lr][nt * 16 + quad * 4]);
                    Oacc[d] = __builtin_amdgcn_mfma_f32_16x16x16f16(pa[nt], vf, Oacc[d], 0, 0, 0);
                }
#pragma unroll
            for (int nt = 0; nt < 4; nt++)
                lacc = __builtin_amdgcn_mfma_f32_16x16x16f16(pa[nt], ones, lacc, 0, 0, 0);
            __builtin_amdgcn_s_setprio(0);
        }
    }

    // epilogue: O / l -> ob [B, L, H*HD] bf16  (row=q=quad*4+r, col=d=lr)
    const int b = bh >> 4, h = bh & 15;
#pragma unroll
    for (int r = 0; r < 4; r++) {
        const float inv = 1.0f / lacc[r];
        const int q = qbase + quad * 4 + r;
        bf16_t* op = ob + ((size_t)(b * LQ + q)) * 1024 + h * 64;
#pragma unroll
        for (int d = 0; d < 4; d++)
            op[d * 16 + lr] = (bf16_t)(Oacc[d][r] * inv);
    }
}

// ---------------- launch -----------------------------------------------------
extern "C" void kernel_launch(void* const* d_in, const int* in_sizes, int n_in,
                              void* d_out, int out_size, void* d_ws, size_t ws_size,
                              hipStream_t stream) {
    const float* x        = (const float*)d_in[0];
    const float* rope_cos = (const float*)d_in[1];
    const float* rope_sin = (const float*)d_in[2];
    const float* W_qkv    = (const float*)d_in[3];
    const float* W_out    = (const float*)d_in[4];
    const float* b_out    = (const float*)d_in[5];
    float* out = (float*)d_out;

    // ws (bytes): xb 8M | qb 8M | kb 8M | vth 8M | ob 8M | Wqkvt 6M | Wot 2M | rpk 0.5M
    char* wsb = (char*)d_ws;
    bf16_t* xb    = (bf16_t*)(wsb);
    bf16_t* qbf   = (bf16_t*)(wsb + ((size_t)8  << 20));
    bf16_t* kbf   = (bf16_t*)(wsb + ((size_t)16 << 20));
    f16_t*  vth   = (f16_t*) (wsb + ((size_t)24 << 20));
    bf16_t* ob    = (bf16_t*)(wsb + ((size_t)32 << 20));
    bf16_t* Wqkvt = (bf16_t*)(wsb + ((size_t)40 << 20));
    bf16_t* Wot   = (bf16_t*)(wsb + ((size_t)46 << 20));
    float4* rpk   = (float4*)(wsb + ((size_t)48 << 20));

    prep_kernel<<<8320, 256, 0, stream>>>(x, W_qkv, W_out, rope_cos, rope_sin,
                                          xb, Wqkvt, Wot, rpk);

    dim3 g1(3072 / 128, 4096 / 128);
    qkv_gemm_kernel<<<g1, 256, 0, stream>>>(xb, Wqkvt, qbf, kbf, vth, rpk);

    dim3 g2(32, 16);   // x = bh (L2 locality), y -> qt2 = 15-y (heavy first)
    attn_kernel10<<<g2, 512, 0, stream>>>(qbf, kbf, vth, ob);

    dim3 g3(1024 / 128, 4096 / 64);
    out_gemm_kernel<<<g3, 256, 0, stream>>>(ob, Wot, out, b_out);
}

// Round 10
// 172.057 us; speedup vs baseline: 1.0842x; 1.0141x over previous
//
#include <hip/hip_runtime.h>
#include <math.h>

// Problem constants
#define BQ 2
#define LQ 2048
#define DQ 1024
#define HQ 16
#define HDQ 64

typedef __bf16 bf16_t;
typedef bf16_t bf16x4 __attribute__((ext_vector_type(4)));
typedef bf16_t bf16x8 __attribute__((ext_vector_type(8)));
typedef _Float16 f16_t;
typedef f16_t f16x4 __attribute__((ext_vector_type(4)));
typedef f16_t f16x8 __attribute__((ext_vector_type(8)));
typedef float f32x4 __attribute__((ext_vector_type(4)));

// ---------------- fused prep: x->bf16, W transposes, packed rope table ------
// grid 8320: [0,4096) convert x | [4096,7168) Wqkv^T | [7168,8192) Wout^T |
// [8192,8320) rope pack rpk[l*16+i] = (cos_i, cos_{16+i}, sin_i, sin_{16+i})
__global__ __launch_bounds__(256) void prep_kernel(
    const float* __restrict__ x, const float* __restrict__ Wqkv,
    const float* __restrict__ Wout, const float* __restrict__ cosT,
    const float* __restrict__ sinT,
    bf16_t* __restrict__ xb, bf16_t* __restrict__ Wqkvt,
    bf16_t* __restrict__ Wot, float4* __restrict__ rpk)
{
    __shared__ float t[32][33];
    const int bid = blockIdx.x, tid = threadIdx.x;
    if (bid < 4096) {
        const int i = (bid * 256 + tid) * 4;
        float4 v = *(const float4*)(x + i);
        bf16x4 o;
        o[0] = (bf16_t)v.x; o[1] = (bf16_t)v.y; o[2] = (bf16_t)v.z; o[3] = (bf16_t)v.w;
        *(bf16x4*)(xb + i) = o;
    } else if (bid < 8192) {
        const bool isq = bid < 7168;
        const int b = isq ? bid - 4096 : bid - 7168;
        const int N = isq ? 3072 : 1024;
        const int gx = isq ? 96 : 32;
        const float* in = isq ? Wqkv : Wout;
        bf16_t* out = isq ? Wqkvt : Wot;
        const int k0 = (b / gx) * 32, n0 = (b % gx) * 32;
        const int r = tid >> 3, c4 = (tid & 7) * 4;
        float4 v = *(const float4*)(in + (size_t)(k0 + r) * N + n0 + c4);
        t[r][c4 + 0] = v.x; t[r][c4 + 1] = v.y;
        t[r][c4 + 2] = v.z; t[r][c4 + 3] = v.w;
        __syncthreads();
        bf16x4 o;
        o[0] = (bf16_t)t[c4 + 0][r]; o[1] = (bf16_t)t[c4 + 1][r];
        o[2] = (bf16_t)t[c4 + 2][r]; o[3] = (bf16_t)t[c4 + 3][r];
        *(bf16x4*)(out + (size_t)(n0 + r) * 1024 + k0 + c4) = o;
    } else {
        const int idx = (bid - 8192) * 256 + tid;   // 0..32767
        const int i = idx & 15, l = idx >> 4;
        rpk[idx] = make_float4(cosT[l * 64 + i], cosT[l * 64 + 16 + i],
                               sinT[l * 64 + i], sinT[l * 64 + 16 + i]);
    }
}

// ---------------- QKV GEMM: 128x128, BK=32 dbuf, 1 barrier/iter -------------
// T1 XCD-chunked swizzle: HW dispatches linear bid round-robin over 8 XCDs
// (bid%8 = XCD). Remap wid=(bid%8)*96+bid/8 so each XCD owns 4 contiguous
// m-panels x all 24 n-tiles -> A-panel fetched once per XCD (FETCH was 43 MB
// vs 14 MB unique = 3x cross-L2 duplication). Bijective (768%8==0).
// Per iter: {issue loads t+2 -> regs | ds_read frags buf[cur] | 16 MFMA |
// ds_write tile t+1 -> buf[cur^1] | ONE barrier}. Swizzle (4-chunk rows):
// store chunk c^((row>>1)&3), read chunk quad^((lr>>1)&3) -> conflict-free.
__global__ __launch_bounds__(256) void qkv_gemm_kernel(
    const bf16_t* __restrict__ A, const bf16_t* __restrict__ Bt,
    bf16_t* __restrict__ qo, bf16_t* __restrict__ ko, f16_t* __restrict__ vo,
    const float4* __restrict__ rpk)
{
    __shared__ __align__(16) bf16_t As[2][128][32];
    __shared__ __align__(16) bf16_t Bs[2][128][32];
    const int K = 1024;
    const int tid  = threadIdx.x;
    const int lane = tid & 63;
    const int w    = tid >> 6;
    const int lr   = lane & 15, quad = lane >> 4;
    const int wm   = w & 1, wn = w >> 1;

    // XCD-chunked block remap (grid 24 x 32 = 768 blocks, 96 per XCD)
    const int bid0 = blockIdx.x + 24 * blockIdx.y;
    const int wid  = (bid0 & 7) * 96 + (bid0 >> 3);
    const int m0   = (wid / 24) * 128, n0 = (wid % 24) * 128;

    const int sr  = tid >> 2;                      // 0..63
    const int sc  = tid & 3;                       // chunk 0..3
    const int sw  = (sc ^ ((sr >> 1) & 3)) * 8;    // swizzled LDS col
    const int rdc = (quad ^ ((lr >> 1) & 3)) * 8;  // frag-read col

    const bf16_t* Ar0 = A  + (size_t)(m0 + sr) * K + sc * 8;
    const bf16_t* Ar1 = A  + (size_t)(m0 + sr + 64) * K + sc * 8;
    const bf16_t* Br0 = Bt + (size_t)(n0 + sr) * K + sc * 8;
    const bf16_t* Br1 = Bt + (size_t)(n0 + sr + 64) * K + sc * 8;

    f32x4 acc[4][4];
#pragma unroll
    for (int i = 0; i < 4; i++)
#pragma unroll
        for (int j = 0; j < 4; j++)
#pragma unroll
            for (int r = 0; r < 4; r++) acc[i][j][r] = 0.f;

#define QLOAD(A0, A1, B0, B1, t) do {                      \
        A0 = *(const bf16x8*)(Ar0 + (t) * 32);             \
        A1 = *(const bf16x8*)(Ar1 + (t) * 32);             \
        B0 = *(const bf16x8*)(Br0 + (t) * 32);             \
        B1 = *(const bf16x8*)(Br1 + (t) * 32);             \
    } while (0)
#define QWRITE(A0, A1, B0, B1, bf) do {                    \
        *(bf16x8*)(&As[bf][sr][sw])      = A0;             \
        *(bf16x8*)(&As[bf][sr + 64][sw]) = A1;             \
        *(bf16x8*)(&Bs[bf][sr][sw])      = B0;             \
        *(bf16x8*)(&Bs[bf][sr + 64][sw]) = B1;             \
    } while (0)
#define QCOMP(bf) do {                                                        \
        bf16x8 af[4], bfr[4];                                                 \
        _Pragma("unroll")                                                     \
        for (int tt = 0; tt < 4; tt++) {                                      \
            af[tt]  = *(const bf16x8*)(&As[bf][wm * 64 + tt * 16 + lr][rdc]); \
            bfr[tt] = *(const bf16x8*)(&Bs[bf][wn * 64 + tt * 16 + lr][rdc]); \
        }                                                                     \
        _Pragma("unroll")                                                     \
        for (int mt = 0; mt < 4; mt++)                                        \
            _Pragma("unroll")                                                 \
            for (int nt = 0; nt < 4; nt++)                                    \
                acc[mt][nt] = __builtin_amdgcn_mfma_f32_16x16x32_bf16(        \
                    af[mt], bfr[nt], acc[mt][nt], 0, 0, 0);                   \
    } while (0)

    bf16x8 a00, a10, b00, b10;   // staging set 0 (even tiles)
    bf16x8 a01, a11, b01, b11;   // staging set 1 (odd tiles)
    QLOAD(a00, a10, b00, b10, 0);
    QLOAD(a01, a11, b01, b11, 1);
    QWRITE(a00, a10, b00, b10, 0);
    __syncthreads();

    for (int t = 0; t < 32; t += 2) {
        if (t + 2 < 32) QLOAD(a00, a10, b00, b10, t + 2);
        QCOMP(0);
        QWRITE(a01, a11, b01, b11, 1);      // tile t+1 (2 iters in flight)
        __syncthreads();
        if (t + 3 < 32) QLOAD(a01, a11, b01, b11, t + 3);
        QCOMP(1);
        if (t + 2 < 32) QWRITE(a00, a10, b00, b10, 0);
        __syncthreads();
    }
#undef QLOAD
#undef QWRITE
#undef QCOMP

    const int which = n0 >> 10;                          // 0=q 1=k 2=v
    const int h = ((n0 & 1023) + wn * 64) >> 6;          // wave-uniform head
    if (which == 2) {
        // V: store transposed fp16 [B,H,HD,L]; r=0..3 consecutive l -> f16x4
#pragma unroll
        for (int mt = 0; mt < 4; mt++) {
            const int m = m0 + wm * 64 + mt * 16 + quad * 4;
            const int b = m >> 11, l = m & 2047;
            f16_t* p = vo + ((size_t)(b * HQ + h) * HDQ) * LQ + l;
#pragma unroll
            for (int nt = 0; nt < 4; nt++) {
                f16x4 pv;
#pragma unroll
                for (int r = 0; r < 4; r++) pv[r] = (f16_t)acc[mt][nt][r];
                *(f16x4*)(p + (size_t)(nt * 16 + lr) * LQ) = pv;
            }
        }
    } else {
        // Q/K: fused RoPE via packed table; Q gets softmax prescale
        bf16_t* dst = which ? ko : qo;
        const float qs = which ? 1.0f : 0.18033688011f;  // 0.125*log2(e)
#pragma unroll
        for (int mt = 0; mt < 4; mt++)
#pragma unroll
            for (int r = 0; r < 4; r++) {
                const int m = m0 + wm * 64 + mt * 16 + quad * 4 + r;
                const int b = m >> 11, l = m & 2047;
                const float4 rp = rpk[l * 16 + lr];
                const float a0 = acc[mt][0][r], a1 = acc[mt][1][r];
                const float a2 = acc[mt][2][r], a3 = acc[mt][3][r];
                bf16_t* p = dst + ((size_t)(b * HQ + h) * LQ + l) * HDQ;
                p[lr]      = (bf16_t)((a0 * rp.x - a2 * rp.z) * qs);
                p[16 + lr] = (bf16_t)((a1 * rp.y - a3 * rp.w) * qs);
                p[32 + lr] = (bf16_t)((a2 * rp.x + a0 * rp.z) * qs);
                p[48 + lr] = (bf16_t)((a3 * rp.y + a1 * rp.w) * qs);
            }
    }
}

// ---------------- Out GEMM: 64x128, BK=32 dbuf, 1 barrier/iter --------------
// Same pipeline/swizzle as qkv BK=32; T1 XCD-chunked remap (512 blocks,
// 64 per XCD -> each XCD owns 8 contiguous m-panels x all 8 n-tiles).
__global__ __launch_bounds__(256) void out_gemm_kernel(
    const bf16_t* __restrict__ A, const bf16_t* __restrict__ Bt,
    float* __restrict__ fo, const float* __restrict__ bias)
{
    __shared__ __align__(16) bf16_t As[2][64][32];
    __shared__ __align__(16) bf16_t Bs[2][128][32];
    const int K = 1024, N = 1024;
    const int tid  = threadIdx.x;
    const int lane = tid & 63;
    const int w    = tid >> 6;
    const int lr   = lane & 15, quad = lane >> 4;

    // XCD-chunked block remap (grid 8 x 64 = 512 blocks, 64 per XCD)
    const int bid0 = blockIdx.x + 8 * blockIdx.y;
    const int wid  = (bid0 & 7) * 64 + (bid0 >> 3);
    const int m0   = (wid >> 3) * 64, n0 = (wid & 7) * 128;

    const int sr  = tid >> 2;                      // 0..63
    const int sc  = tid & 3;                       // chunk 0..3
    const int sw  = (sc ^ ((sr >> 1) & 3)) * 8;    // swizzled LDS col
    const int rdc = (quad ^ ((lr >> 1) & 3)) * 8;  // frag-read col

    const bf16_t* Ar0 = A  + (size_t)(m0 + sr) * K + sc * 8;
    const bf16_t* Br0 = Bt + (size_t)(n0 + sr) * K + sc * 8;
    const bf16_t* Br1 = Bt + (size_t)(n0 + sr + 64) * K + sc * 8;

    f32x4 acc[4][2];
#pragma unroll
    for (int i = 0; i < 4; i++)
#pragma unroll
        for (int j = 0; j < 2; j++)
#pragma unroll
            for (int r = 0; r < 4; r++) acc[i][j][r] = 0.f;

#define OLOAD(A0, B0, B1, t) do {                          \
        A0 = *(const bf16x8*)(Ar0 + (t) * 32);             \
        B0 = *(const bf16x8*)(Br0 + (t) * 32);             \
        B1 = *(const bf16x8*)(Br1 + (t) * 32);             \
    } while (0)
#define OWRITE(A0, B0, B1, bf) do {                        \
        *(bf16x8*)(&As[bf][sr][sw])      = A0;             \
        *(bf16x8*)(&Bs[bf][sr][sw])      = B0;             \
        *(bf16x8*)(&Bs[bf][sr + 64][sw]) = B1;             \
    } while (0)
#define OCOMP(bf) do {                                                        \
        bf16x8 af[4], bfr[2];                                                 \
        _Pragma("unroll")                                                     \
        for (int tt = 0; tt < 4; tt++)                                        \
            af[tt]  = *(const bf16x8*)(&As[bf][tt * 16 + lr][rdc]);           \
        _Pragma("unroll")                                                     \
        for (int tt = 0; tt < 2; tt++)                                        \
            bfr[tt] = *(const bf16x8*)(&Bs[bf][w * 32 + tt * 16 + lr][rdc]);  \
        _Pragma("unroll")                                                     \
        for (int mt = 0; mt < 4; mt++)                                        \
            _Pragma("unroll")                                                 \
            for (int nt = 0; nt < 2; nt++)                                    \
                acc[mt][nt] = __builtin_amdgcn_mfma_f32_16x16x32_bf16(        \
                    af[mt], bfr[nt], acc[mt][nt], 0, 0, 0);                   \
    } while (0)

    bf16x8 a0s0, b0s0, b1s0;
    bf16x8 a0s1, b0s1, b1s1;
    OLOAD(a0s0, b0s0, b1s0, 0);
    OLOAD(a0s1, b0s1, b1s1, 1);
    OWRITE(a0s0, b0s0, b1s0, 0);
    __syncthreads();

    for (int t = 0; t < 32; t += 2) {
        if (t + 2 < 32) OLOAD(a0s0, b0s0, b1s0, t + 2);
        OCOMP(0);
        OWRITE(a0s1, b0s1, b1s1, 1);
        __syncthreads();
        if (t + 3 < 32) OLOAD(a0s1, b0s1, b1s1, t + 3);
        OCOMP(1);
        if (t + 2 < 32) OWRITE(a0s0, b0s0, b1s0, 0);
        __syncthreads();
    }
#undef OLOAD
#undef OWRITE
#undef OCOMP

#pragma unroll
    for (int nt = 0; nt < 2; nt++) {
        const int n = n0 + w * 32 + nt * 16 + lr;
        const float bj = bias[n];
#pragma unroll
        for (int mt = 0; mt < 4; mt++)
#pragma unroll
            for (int r = 0; r < 4; r++) {
                const int m = m0 + mt * 16 + quad * 4 + r;
                fo[(size_t)m * N + n] = acc[mt][nt][r] + bj;
            }
    }
}

// ---------------- bf16/fp16 MFMA flash attention v10 ------------------------
// v10: V tile pad 64 -> 68 f16 (136 B row = 34 banks) — fixed the 4.33M
// conflict cycles (R4->R5: attn -7 us, conflict theory exact-match).
// K tile keeps the verified XOR-swizzle. setprio kept.
__global__ __launch_bounds__(512) void attn_kernel10(
    const bf16_t* __restrict__ qb, const bf16_t* __restrict__ kb,
    const f16_t* __restrict__ vtb, bf16_t* __restrict__ ob)
{
    __shared__ __align__(16) bf16_t Kb[2][64][64];
    __shared__ __align__(16) f16_t  Vs[2][64][68];

    const int tid  = threadIdx.x;
    const int lane = tid & 63;
    const int w    = tid >> 6;           // 0..7
    const int quad = lane >> 4;
    const int lr   = lane & 15;
    const int bh   = blockIdx.x;
    const int qt2  = 15 - blockIdx.y;    // heavy blocks first

    const bf16_t* Kh = kb  + (size_t)bh * LQ * HDQ;
    const f16_t*  Vh = vtb + (size_t)bh * HDQ * LQ;

    const int r0  = tid >> 3;                    // 0..63
    const int c0  = (tid & 7) * 8;
    const int ksw = ((tid & 7) ^ (r0 & 7)) * 8;  // swizzled chunk (K store)

    f16x4 ones;
#pragma unroll
    for (int j = 0; j < 4; j++) ones[j] = (f16_t)1.0f;

    const int qbase = qt2 * 128 + w * 16;        // wave's first q row
    const int qrow  = qbase + lr;
    const bf16_t* qp = qb + ((size_t)bh * LQ + qrow) * HDQ;
    const bf16x8 qa0 = *(const bf16x8*)(qp + quad * 8);
    const bf16x8 qa1 = *(const bf16x8*)(qp + 32 + quad * 8);

    const int nkt = 2 * qt2 + 2;                 // kv tiles for this block

    bf16x8 kp = *(const bf16x8*)(Kh + (size_t)r0 * HDQ + c0);
    f16x8  vp = *(const f16x8*)(Vh + (size_t)r0 * LQ + c0);

    f32x4 Oacc[4], lacc;
#pragma unroll
    for (int d = 0; d < 4; d++)
#pragma unroll
        for (int r = 0; r < 4; r++) Oacc[d][r] = 0.f;
#pragma unroll
    for (int r = 0; r < 4; r++) lacc[r] = 0.f;

    for (int kt = 0; kt < nkt; kt++) {
        const int buf = kt & 1;
        *(bf16x8*)(&Kb[buf][r0][ksw]) = kp;
        *(f16x8*)(&Vs[buf][r0][c0]) = vp;
        __syncthreads();
        if (kt + 1 < nkt) {
            kp = *(const bf16x8*)(Kh + (size_t)((kt + 1) * 64 + r0) * HDQ + c0);
            vp = *(const f16x8*)(Vh + (size_t)r0 * LQ + (kt + 1) * 64 + c0);
        }

        if (kt * 64 <= qbase + 15) {             // else fully masked: skip
            // S^T = K Q^T  (row=kv=quad*4+r, col=q=lr), exp2-domain
            f32x4 s[4];
            __builtin_amdgcn_s_setprio(1);
#pragma unroll
            for (int nt = 0; nt < 4; nt++) {
                const int rsw = lr & 7;          // row&7 of K frag row
                const bf16x8 kf0 = *(const bf16x8*)(&Kb[buf][nt * 16 + lr][(quad ^ rsw) * 8]);
                const bf16x8 kf1 = *(const bf16x8*)(&Kb[buf][nt * 16 + lr][((quad + 4) ^ rsw) * 8]);
                f32x4 z = {0.f, 0.f, 0.f, 0.f};
                z = __builtin_amdgcn_mfma_f32_16x16x32_bf16(kf0, qa0, z, 0, 0, 0);
                z = __builtin_amdgcn_mfma_f32_16x16x32_bf16(kf1, qa1, z, 0, 0, 0);
                s[nt] = z;
            }
            __builtin_amdgcn_s_setprio(0);
            if (kt * 64 + 63 > qbase) {          // partial diagonal tile
#pragma unroll
                for (int nt = 0; nt < 4; nt++)
#pragma unroll
                    for (int r = 0; r < 4; r++)
                        if (kt * 64 + nt * 16 + quad * 4 + r > qrow) s[nt][r] = -INFINITY;
            }
            f16x4 pa[4];
#pragma unroll
            for (int nt = 0; nt < 4; nt++)
#pragma unroll
                for (int r = 0; r < 4; r++)
                    pa[nt][r] = (f16_t)__builtin_amdgcn_exp2f(s[nt][r]);

            // O += P V (16x16x16 f16), l += row-sum(P)
            __builtin_amdgcn_s_setprio(1);
#pragma unroll
            for (int d = 0; d < 4; d++)
#pragma unroll
                for (int nt = 0; nt < 4; nt++) {
                    const f16x4 vf = *(const f16x4*)(&Vs[buf][d * 16 + lr][nt * 16 + quad * 4]);
                    Oacc[d] = __builtin_amdgcn_mfma_f32_16x16x16f16(pa[nt], vf, Oacc[d], 0, 0, 0);
                }
#pragma unroll
            for (int nt = 0; nt < 4; nt++)
                lacc = __builtin_amdgcn_mfma_f32_16x16x16f16(pa[nt], ones, lacc, 0, 0, 0);
            __builtin_amdgcn_s_setprio(0);
        }
    }

    // epilogue: O / l -> ob [B, L, H*HD] bf16  (row=q=quad*4+r, col=d=lr)
    const int b = bh >> 4, h = bh & 15;
#pragma unroll
    for (int r = 0; r < 4; r++) {
        const float inv = 1.0f / lacc[r];
        const int q = qbase + quad * 4 + r;
        bf16_t* op = ob + ((size_t)(b * LQ + q)) * 1024 + h * 64;
#pragma unroll
        for (int d = 0; d < 4; d++)
            op[d * 16 + lr] = (bf16_t)(Oacc[d][r] * inv);
    }
}

// ---------------- launch -----------------------------------------------------
extern "C" void kernel_launch(void* const* d_in, const int* in_sizes, int n_in,
                              void* d_out, int out_size, void* d_ws, size_t ws_size,
                              hipStream_t stream) {
    const float* x        = (const float*)d_in[0];
    const float* rope_cos = (const float*)d_in[1];
    const float* rope_sin = (const float*)d_in[2];
    const float* W_qkv    = (const float*)d_in[3];
    const float* W_out    = (const float*)d_in[4];
    const float* b_out    = (const float*)d_in[5];
    float* out = (float*)d_out;

    // ws (bytes): xb 8M | qb 8M | kb 8M | vth 8M | ob 8M | Wqkvt 6M | Wot 2M | rpk 0.5M
    char* wsb = (char*)d_ws;
    bf16_t* xb    = (bf16_t*)(wsb);
    bf16_t* qbf   = (bf16_t*)(wsb + ((size_t)8  << 20));
    bf16_t* kbf   = (bf16_t*)(wsb + ((size_t)16 << 20));
    f16_t*  vth   = (f16_t*) (wsb + ((size_t)24 << 20));
    bf16_t* ob    = (bf16_t*)(wsb + ((size_t)32 << 20));
    bf16_t* Wqkvt = (bf16_t*)(wsb + ((size_t)40 << 20));
    bf16_t* Wot   = (bf16_t*)(wsb + ((size_t)46 << 20));
    float4* rpk   = (float4*)(wsb + ((size_t)48 << 20));

    prep_kernel<<<8320, 256, 0, stream>>>(x, W_qkv, W_out, rope_cos, rope_sin,
                                          xb, Wqkvt, Wot, rpk);

    dim3 g1(3072 / 128, 4096 / 128);
    qkv_gemm_kernel<<<g1, 256, 0, stream>>>(xb, Wqkvt, qbf, kbf, vth, rpk);

    dim3 g2(32, 16);   // x = bh (L2 locality), y -> qt2 = 15-y (heavy first)
    attn_kernel10<<<g2, 512, 0, stream>>>(qbf, kbf, vth, ob);

    dim3 g3(1024 / 128, 4096 / 64);
    out_gemm_kernel<<<g3, 256, 0, stream>>>(ob, Wot, out, b_out);
}